// Round 1
// baseline (12711.449 us; speedup 1.0000x reference)
//
#include <hip/hip_runtime.h>

// Problem constants (from reference): T=512, N=1024, MC=512, H=5, M=20, NF=20
#define T_DIM 512
#define N_DIM 1024
#define MC_DIM 512
#define H_DIM 5
#define M_WIN 20
#define NF_DIM 20

typedef __attribute__((ext_vector_type(8))) short short8;
typedef __attribute__((ext_vector_type(4))) float f32x4;

__device__ __forceinline__ unsigned short f2bf(float f) {
  unsigned int u = __float_as_uint(f);
  u += 0x7fffu + ((u >> 16) & 1u);   // round-to-nearest-even
  return (unsigned short)(u >> 16);
}
__device__ __forceinline__ float bf2f(unsigned short s) {
  return __uint_as_float(((unsigned int)s) << 16);
}

// ---------------------------------------------------------------------------
// WW[t,i,n] = sum_k phi[k,i] * Wpad[t+k, n]  (bf16 out, layout [t][i][n])
// grid (N/256, T)
__global__ __launch_bounds__(256) void ww_kernel(const float* __restrict__ W,
                                                 const float* __restrict__ phi,
                                                 unsigned short* __restrict__ WWb) {
  __shared__ float phis[M_WIN * H_DIM];
  int tid = threadIdx.x;
  if (tid < M_WIN * H_DIM) phis[tid] = phi[tid];
  __syncthreads();
  int n = blockIdx.x * 256 + tid;
  int t = blockIdx.y;
  float acc[H_DIM] = {0.f, 0.f, 0.f, 0.f, 0.f};
  int k0 = 19 - t; if (k0 < 0) k0 = 0;
  for (int k = k0; k < M_WIN; ++k) {
    float wv = W[(t + k - 19) * N_DIM + n];
#pragma unroll
    for (int i = 0; i < H_DIM; ++i) acc[i] += phis[k * H_DIM + i] * wv;
  }
#pragma unroll
  for (int i = 0; i < H_DIM; ++i)
    WWb[(size_t)(t * H_DIM + i) * N_DIM + n] = f2bf(acc[i]);
}

// Esc[c,i,n] = sigma[i]^0.25 * E[c,n,i]   (bf16 out, layout [c][i][n])
// grid (N/256, MC)
__global__ __launch_bounds__(256) void esc_kernel(const float* __restrict__ E,
                                                  const float* __restrict__ sigma,
                                                  unsigned short* __restrict__ Escb) {
  int tid = threadIdx.x;
  int n = blockIdx.x * 256 + tid;
  int c = blockIdx.y;
#pragma unroll
  for (int i = 0; i < H_DIM; ++i) {
    float s4 = powf(sigma[i], 0.25f);
    float v = E[((size_t)c * N_DIM + n) * H_DIM + i] * s4;
    Escb[(size_t)(c * H_DIM + i) * N_DIM + n] = f2bf(v);
  }
}

// Et2[n][(f,c)] = E_stu[f,c,n]  fp32 (10240 x 1024) -> bf16 (1024 x 10240) transpose
// grid (10240/32, 1024/32), block 256 (32x8)
__global__ __launch_bounds__(256) void transpose_conv_kernel(const float* __restrict__ in,
                                                             unsigned short* __restrict__ out) {
  __shared__ float tile[32][33];
  int tx = threadIdx.x & 31, ty = threadIdx.x >> 5;
  int d0 = blockIdx.x * 32, n0 = blockIdx.y * 32;
#pragma unroll
  for (int k = 0; k < 4; ++k) {
    int r = ty + k * 8;
    tile[r][tx] = in[(size_t)(d0 + r) * N_DIM + n0 + tx];
  }
  __syncthreads();
#pragma unroll
  for (int k = 0; k < 4; ++k) {
    int r = ty + k * 8;
    out[(size_t)(n0 + r) * 10240 + d0 + tx] = f2bf(tile[tx][r]);
  }
}

// ---------------------------------------------------------------------------
// Generic C(MxN) = A(MxD) * B(NxD)^T, bf16 MFMA 16x16x32, 128x128 tile, BK=32.
// AF32/BF32: operand is fp32 in global, converted to bf16 during LDS staging.
// grid (N/128, M/128, split); kChunk = D/split (mult of 32). useAtomic for split>1.
template <bool AF32, bool BF32>
__global__ __launch_bounds__(256) void gemm_bt(const void* __restrict__ Ap,
                                               const void* __restrict__ Bp,
                                               float* __restrict__ C,
                                               int Ddim, int Ncols, int kChunk, int useAtomic) {
  __shared__ unsigned short As[128 * 32];
  __shared__ unsigned short Bs[128 * 32];
  int tid = threadIdx.x;
  int lane = tid & 63, wave = tid >> 6;
  int wr = (wave >> 1) * 64, wc = (wave & 1) * 64;
  int m0 = blockIdx.y * 128, n0 = blockIdx.x * 128;
  int kBeg = blockIdx.z * kChunk, kEnd = kBeg + kChunk;
  int srow = tid >> 1, scol = (tid & 1) * 16;
  f32x4 zero = {0.f, 0.f, 0.f, 0.f};
  f32x4 acc[4][4];
#pragma unroll
  for (int i = 0; i < 4; ++i)
#pragma unroll
    for (int j = 0; j < 4; ++j) acc[i][j] = zero;

  int fr = lane & 15, fq = lane >> 4;

  for (int kk = kBeg; kk < kEnd; kk += 32) {
    // ---- stage A tile (rows m0.., cols kk..kk+31) ----
    if (AF32) {
      const float* A = (const float*)Ap;
      const float4* src = (const float4*)(A + (size_t)(m0 + srow) * Ddim + kk + scol);
      float4 v0 = src[0], v1 = src[1], v2 = src[2], v3 = src[3];
      float vals[16] = {v0.x, v0.y, v0.z, v0.w, v1.x, v1.y, v1.z, v1.w,
                        v2.x, v2.y, v2.z, v2.w, v3.x, v3.y, v3.z, v3.w};
      unsigned int pk[8];
#pragma unroll
      for (int e = 0; e < 8; ++e)
        pk[e] = (unsigned int)f2bf(vals[2 * e]) | ((unsigned int)f2bf(vals[2 * e + 1]) << 16);
      uint4* dst = (uint4*)&As[srow * 32 + scol];
      dst[0] = make_uint4(pk[0], pk[1], pk[2], pk[3]);
      dst[1] = make_uint4(pk[4], pk[5], pk[6], pk[7]);
    } else {
      const unsigned short* A = (const unsigned short*)Ap;
      const uint4* src = (const uint4*)(A + (size_t)(m0 + srow) * Ddim + kk + scol);
      uint4* dst = (uint4*)&As[srow * 32 + scol];
      dst[0] = src[0];
      dst[1] = src[1];
    }
    // ---- stage B tile (rows n0.., cols kk..kk+31) ----
    if (BF32) {
      const float* B = (const float*)Bp;
      const float4* src = (const float4*)(B + (size_t)(n0 + srow) * Ddim + kk + scol);
      float4 v0 = src[0], v1 = src[1], v2 = src[2], v3 = src[3];
      float vals[16] = {v0.x, v0.y, v0.z, v0.w, v1.x, v1.y, v1.z, v1.w,
                        v2.x, v2.y, v2.z, v2.w, v3.x, v3.y, v3.z, v3.w};
      unsigned int pk[8];
#pragma unroll
      for (int e = 0; e < 8; ++e)
        pk[e] = (unsigned int)f2bf(vals[2 * e]) | ((unsigned int)f2bf(vals[2 * e + 1]) << 16);
      uint4* dst = (uint4*)&Bs[srow * 32 + scol];
      dst[0] = make_uint4(pk[0], pk[1], pk[2], pk[3]);
      dst[1] = make_uint4(pk[4], pk[5], pk[6], pk[7]);
    } else {
      const unsigned short* B = (const unsigned short*)Bp;
      const uint4* src = (const uint4*)(B + (size_t)(n0 + srow) * Ddim + kk + scol);
      uint4* dst = (uint4*)&Bs[srow * 32 + scol];
      dst[0] = src[0];
      dst[1] = src[1];
    }
    __syncthreads();
    // ---- fragments + MFMA: A[m=lane&15][k=quad*8+j], C/D: col=lane&15, row=quad*4+reg ----
    short8 af[4], bf_[4];
#pragma unroll
    for (int i = 0; i < 4; ++i)
      af[i] = *(const short8*)&As[(wr + i * 16 + fr) * 32 + fq * 8];
#pragma unroll
    for (int j = 0; j < 4; ++j)
      bf_[j] = *(const short8*)&Bs[(wc + j * 16 + fr) * 32 + fq * 8];
#pragma unroll
    for (int i = 0; i < 4; ++i)
#pragma unroll
      for (int j = 0; j < 4; ++j)
        acc[i][j] = __builtin_amdgcn_mfma_f32_16x16x32_bf16(af[i], bf_[j], acc[i][j], 0, 0, 0);
    __syncthreads();
  }
  // ---- epilogue ----
#pragma unroll
  for (int i = 0; i < 4; ++i) {
#pragma unroll
    for (int j = 0; j < 4; ++j) {
      int mBase = m0 + wr + i * 16 + fq * 4;
      int nIdx = n0 + wc + j * 16 + fr;
#pragma unroll
      for (int r = 0; r < 4; ++r) {
        float v = acc[i][j][r];
        float* p = &C[(size_t)(mBase + r) * Ncols + nIdx];
        if (useAtomic) atomicAdd(p, v);
        else *p = v;
      }
    }
  }
}

// ---------------------------------------------------------------------------
// Sequential feedback loop in MC-dim:  u_t = p_t - y_t ; y_{t+1} = y_t + H_t u_t
// 256 persistent blocks, block b owns rows {2b, 2b+1}; C-slice resident in LDS (bf16).
// Global barrier = per-block monotone flags (agent-scope atomics).
__global__ __launch_bounds__(256) void seq_kernel(const float* __restrict__ Cmat,
                                                  const float* __restrict__ upert,
                                                  const float* __restrict__ bias,
                                                  const float* __restrict__ phi_stu,
                                                  float* __restrict__ U,
                                                  int* __restrict__ flags) {
  __shared__ unsigned short Cl[2 * MC_DIM * NF_DIM];  // [(r*512+c)*20 + f]  (40 KB)
  __shared__ float plds[2][T_DIM];                    // p_t for owned rows (4 KB)
  __shared__ float wlds[NF_DIM];
  __shared__ float red[2][4];
  int tid = threadIdx.x;
  int b = blockIdx.x;
  int c0 = 2 * b, c1 = 2 * b + 1;

  // preload C rows -> LDS bf16 (idx = f*1024 + r*512 + c, c fastest => coalesced)
  for (int idx = tid; idx < 2 * MC_DIM * NF_DIM; idx += 256) {
    int f = idx / 1024;
    int rem = idx - f * 1024;
    int r = rem >> 9;
    int c = rem & 511;
    float v = Cmat[(size_t)(c0 + r) * 10240 + f * 512 + c];
    Cl[(r * 512 + c) * NF_DIM + f] = f2bf(v);
  }
  for (int t = tid; t < T_DIM; t += 256) {
    plds[0][t] = upert[(size_t)t * MC_DIM + c0] + bias[c0];
    plds[1][t] = upert[(size_t)t * MC_DIM + c1] + bias[c1];
  }
  __syncthreads();

  float y0 = 0.f, y1 = 0.f;   // state lives in thread 0's registers
  int ca = tid, cb = tid + 256;
  int wv = tid >> 6, ln = tid & 63;

  for (int t = 0; t < T_DIM; ++t) {
    if (tid == 0) {
      float u0 = plds[0][t] - y0;
      float u1 = plds[1][t] - y1;
      __hip_atomic_store(&U[(size_t)t * MC_DIM + c0], u0, __ATOMIC_RELAXED, __HIP_MEMORY_SCOPE_AGENT);
      __hip_atomic_store(&U[(size_t)t * MC_DIM + c1], u1, __ATOMIC_RELAXED, __HIP_MEMORY_SCOPE_AGENT);
      __hip_atomic_store(&flags[b], t + 1, __ATOMIC_RELEASE, __HIP_MEMORY_SCOPE_AGENT);
    }
    if (t == T_DIM - 1) break;
    if (tid < NF_DIM) wlds[tid] = phi_stu[t * NF_DIM + tid];
    // wait for all 256 blocks to publish u_t  (thread i watches flags[i])
    while (__hip_atomic_load(&flags[tid], __ATOMIC_ACQUIRE, __HIP_MEMORY_SCOPE_AGENT) < t + 1) {
      __builtin_amdgcn_s_sleep(1);
    }
    __syncthreads();
    float ua = __hip_atomic_load(&U[(size_t)t * MC_DIM + ca], __ATOMIC_RELAXED, __HIP_MEMORY_SCOPE_AGENT);
    float ub = __hip_atomic_load(&U[(size_t)t * MC_DIM + cb], __ATOMIC_RELAXED, __HIP_MEMORY_SCOPE_AGENT);
    float p0 = 0.f, p1 = 0.f;
    const unsigned short* b0a = &Cl[(0 * 512 + ca) * NF_DIM];
    const unsigned short* b0b = &Cl[(0 * 512 + cb) * NF_DIM];
    const unsigned short* b1a = &Cl[(512 + ca) * NF_DIM];
    const unsigned short* b1b = &Cl[(512 + cb) * NF_DIM];
#pragma unroll
    for (int f = 0; f < NF_DIM; ++f) {
      float wf = wlds[f];
      p0 += wf * (bf2f(b0a[f]) * ua + bf2f(b0b[f]) * ub);
      p1 += wf * (bf2f(b1a[f]) * ua + bf2f(b1b[f]) * ub);
    }
#pragma unroll
    for (int off = 32; off > 0; off >>= 1) {
      p0 += __shfl_down(p0, off);
      p1 += __shfl_down(p1, off);
    }
    if (ln == 0) { red[0][wv] = p0; red[1][wv] = p1; }
    __syncthreads();
    if (tid == 0) {
      y0 += red[0][0] + red[0][1] + red[0][2] + red[0][3];
      y1 += red[1][0] + red[1][1] + red[1][2] + red[1][3];
    }
  }
}

// Rp[t][(f,c)] = phi_stu[t,f] * U[t,c]   (bf16)   grid (10240/256, T)
__global__ __launch_bounds__(256) void rp_kernel(const float* __restrict__ U,
                                                 const float* __restrict__ phi_stu,
                                                 unsigned short* __restrict__ Rp) {
  int t = blockIdx.y;
  int j = blockIdx.x * 256 + threadIdx.x;
  int f = j >> 9, c = j & 511;
  Rp[(size_t)t * 10240 + j] = f2bf(phi_stu[t * NF_DIM + f] * U[(size_t)t * MC_DIM + c]);
}

// ---- chunked exclusive prefix over t of G (T x N) -> X ----
__global__ __launch_bounds__(256) void scan1_kernel(const float* __restrict__ G, float* __restrict__ Psum) {
  int n = blockIdx.x * 256 + threadIdx.x;
  int c = blockIdx.y;
  float s = 0.f;
  for (int j = 0; j < 32; ++j) s += G[(size_t)(c * 32 + j) * N_DIM + n];
  Psum[c * N_DIM + n] = s;
}
__global__ __launch_bounds__(256) void scan2_kernel(float* __restrict__ Psum) {
  int n = blockIdx.x * 256 + threadIdx.x;
  float run = 0.f;
  for (int c = 0; c < 16; ++c) {
    float v = Psum[c * N_DIM + n];
    Psum[c * N_DIM + n] = run;
    run += v;
  }
}
__global__ __launch_bounds__(256) void scan3_kernel(const float* __restrict__ G, const float* __restrict__ Psum,
                                                    float* __restrict__ X) {
  int n = blockIdx.x * 256 + threadIdx.x;
  int c = blockIdx.y;
  float x = Psum[c * N_DIM + n];
  for (int j = 0; j < 32; ++j) {
    int t = c * 32 + j;
    X[(size_t)t * N_DIM + n] = x;
    x += G[(size_t)t * N_DIM + n];
  }
}

// losses[t] = dot(XQ[t], X[t]) + dot(UR[t], U[t])
__global__ __launch_bounds__(256) void loss_kernel(const float* __restrict__ XQ, const float* __restrict__ X,
                                                   const float* __restrict__ UR, const float* __restrict__ U,
                                                   float* __restrict__ out) {
  int t = blockIdx.x, tid = threadIdx.x;
  float s = 0.f;
  for (int j = tid; j < N_DIM; j += 256) s += XQ[(size_t)t * N_DIM + j] * X[(size_t)t * N_DIM + j];
  for (int c = tid; c < MC_DIM; c += 256) s += UR[(size_t)t * MC_DIM + c] * U[(size_t)t * MC_DIM + c];
#pragma unroll
  for (int off = 32; off > 0; off >>= 1) s += __shfl_down(s, off);
  __shared__ float red[4];
  if ((tid & 63) == 0) red[tid >> 6] = s;
  __syncthreads();
  if (tid == 0) out[t] = red[0] + red[1] + red[2] + red[3];
}

// ---------------------------------------------------------------------------
extern "C" void kernel_launch(void* const* d_in, const int* in_sizes, int n_in,
                              void* d_out, int out_size, void* d_ws, size_t ws_size,
                              hipStream_t stream) {
  const float* Q      = (const float*)d_in[0];
  const float* R      = (const float*)d_in[1];
  const float* Km     = (const float*)d_in[2];
  const float* E      = (const float*)d_in[3];
  const float* bias   = (const float*)d_in[4];
  const float* Estu   = (const float*)d_in[5];
  const float* phi    = (const float*)d_in[6];
  const float* sigma  = (const float*)d_in[7];
  const float* phistu = (const float*)d_in[8];
  const float* W      = (const float*)d_in[9];
  float* out = (float*)d_out;

  char* ws = (char*)d_ws;
  size_t off = 0;
  auto alloc = [&](size_t bytes) -> void* {
    void* p = ws + off;
    off += (bytes + 255) & ~(size_t)255;
    return p;
  };
  int*   flags = (int*)alloc(256 * 4);
  // split-K outputs (contiguous -> single memset)
  float* upert = (float*)alloc((size_t)512 * 512 * 4);    // 1 MB
  float* G     = (float*)alloc((size_t)512 * 1024 * 4);   // 2 MB
  float* XQ    = (float*)alloc((size_t)512 * 1024 * 4);   // 2 MB
  float* UR    = (float*)alloc((size_t)512 * 512 * 4);    // 1 MB
  float* Cmat  = (float*)alloc((size_t)512 * 10240 * 4);  // 20 MB
  float* U     = (float*)alloc((size_t)512 * 512 * 4);    // 1 MB
  float* X     = (float*)alloc((size_t)512 * 1024 * 4);   // 2 MB
  float* Psum  = (float*)alloc((size_t)16 * 1024 * 4);    // 64 KB
  unsigned short* WWb  = (unsigned short*)alloc((size_t)512 * 5120 * 2);   // 5 MB
  unsigned short* Escb = (unsigned short*)alloc((size_t)512 * 5120 * 2);   // 5 MB
  unsigned short* Et2  = (unsigned short*)alloc((size_t)1024 * 10240 * 2); // 20 MB
  unsigned short* Rp   = WWb;  // alias: WWb+Escb (10 MB) dead after GEMM1; Rp needs 10 MB

  hipMemsetAsync(flags, 0, 256 * 4, stream);
  hipMemsetAsync(upert, 0, (size_t)6291456, stream);  // upert,G,XQ,UR

  ww_kernel<<<dim3(4, 512), 256, 0, stream>>>(W, phi, WWb);
  esc_kernel<<<dim3(4, 512), 256, 0, stream>>>(E, sigma, Escb);
  transpose_conv_kernel<<<dim3(320, 32), 256, 0, stream>>>(Estu, Et2);

  // u_pert_raw(512x512) = WW(512x5120) * Esc(512x5120)^T   [split-K 8]
  gemm_bt<false, false><<<dim3(4, 4, 8), 256, 0, stream>>>(WWb, Escb, upert, 5120, 512, 640, 1);
  // Cmat(512x10240) = K(512x1024,f32) * Estu(10240x1024,f32)^T
  gemm_bt<true, true><<<dim3(80, 4, 1), 256, 0, stream>>>(Km, Estu, Cmat, 1024, 10240, 1024, 0);

  // sequential feedback loop -> U (512x512)
  seq_kernel<<<dim3(256), 256, 0, stream>>>(Cmat, upert, bias, phistu, U, flags);

  // G(512x1024) = Rp(512x10240) * Et2(1024x10240)^T   [split-K 4]
  rp_kernel<<<dim3(40, 512), 256, 0, stream>>>(U, phistu, Rp);
  gemm_bt<false, false><<<dim3(8, 4, 4), 256, 0, stream>>>(Rp, Et2, G, 10240, 1024, 2560, 1);

  scan1_kernel<<<dim3(4, 16), 256, 0, stream>>>(G, Psum);
  scan2_kernel<<<dim3(4), 256, 0, stream>>>(Psum);
  scan3_kernel<<<dim3(4, 16), 256, 0, stream>>>(G, Psum, X);

  // XQ(512x1024) = X(512x1024,f32) * Q(1024x1024,f32)^T   [split-K 4]
  gemm_bt<true, true><<<dim3(8, 4, 4), 256, 0, stream>>>(X, Q, XQ, 1024, 1024, 256, 1);
  // UR(512x512)  = U(512x512,f32) * R(512x512,f32)^T      [split-K 8]
  gemm_bt<true, true><<<dim3(4, 4, 8), 256, 0, stream>>>(U, R, UR, 512, 512, 64, 1);

  loss_kernel<<<dim3(512), 256, 0, stream>>>(XQ, X, UR, U, out);
  (void)in_sizes; (void)n_in; (void)out_size; (void)ws_size;
}

// Round 2
// 2104.207 us; speedup vs baseline: 6.0410x; 6.0410x over previous
//
#include <hip/hip_runtime.h>

// Problem constants (from reference): T=512, N=1024, MC=512, H=5, M=20, NF=20
#define T_DIM 512
#define N_DIM 1024
#define MC_DIM 512
#define H_DIM 5
#define M_WIN 20
#define NF_DIM 20

typedef __attribute__((ext_vector_type(8))) short short8;
typedef __attribute__((ext_vector_type(4))) float f32x4;

__device__ __forceinline__ unsigned short f2bf(float f) {
  unsigned int u = __float_as_uint(f);
  u += 0x7fffu + ((u >> 16) & 1u);   // round-to-nearest-even
  return (unsigned short)(u >> 16);
}

// ---------------------------------------------------------------------------
// WW[t,i,n] = sum_k phi[k,i] * Wpad[t+k, n]  (bf16 out, layout [t][i][n])
// grid (N/256, T)
__global__ __launch_bounds__(256) void ww_kernel(const float* __restrict__ W,
                                                 const float* __restrict__ phi,
                                                 unsigned short* __restrict__ WWb) {
  __shared__ float phis[M_WIN * H_DIM];
  int tid = threadIdx.x;
  if (tid < M_WIN * H_DIM) phis[tid] = phi[tid];
  __syncthreads();
  int n = blockIdx.x * 256 + tid;
  int t = blockIdx.y;
  float acc[H_DIM] = {0.f, 0.f, 0.f, 0.f, 0.f};
  int k0 = 19 - t; if (k0 < 0) k0 = 0;
  for (int k = k0; k < M_WIN; ++k) {
    float wv = W[(t + k - 19) * N_DIM + n];
#pragma unroll
    for (int i = 0; i < H_DIM; ++i) acc[i] += phis[k * H_DIM + i] * wv;
  }
#pragma unroll
  for (int i = 0; i < H_DIM; ++i)
    WWb[(size_t)(t * H_DIM + i) * N_DIM + n] = f2bf(acc[i]);
}

// Esc[c,i,n] = sigma[i]^0.25 * E[c,n,i]   (bf16 out, layout [c][i][n])
// grid (N/256, MC)
__global__ __launch_bounds__(256) void esc_kernel(const float* __restrict__ E,
                                                  const float* __restrict__ sigma,
                                                  unsigned short* __restrict__ Escb) {
  int tid = threadIdx.x;
  int n = blockIdx.x * 256 + tid;
  int c = blockIdx.y;
#pragma unroll
  for (int i = 0; i < H_DIM; ++i) {
    float s4 = powf(sigma[i], 0.25f);
    float v = E[((size_t)c * N_DIM + n) * H_DIM + i] * s4;
    Escb[(size_t)(c * H_DIM + i) * N_DIM + n] = f2bf(v);
  }
}

// Et2[n][(f,c)] = E_stu[f,c,n]  fp32 (10240 x 1024) -> bf16 (1024 x 10240) transpose
// grid (10240/32, 1024/32), block 256 (32x8)
__global__ __launch_bounds__(256) void transpose_conv_kernel(const float* __restrict__ in,
                                                             unsigned short* __restrict__ out) {
  __shared__ float tile[32][33];
  int tx = threadIdx.x & 31, ty = threadIdx.x >> 5;
  int d0 = blockIdx.x * 32, n0 = blockIdx.y * 32;
#pragma unroll
  for (int k = 0; k < 4; ++k) {
    int r = ty + k * 8;
    tile[r][tx] = in[(size_t)(d0 + r) * N_DIM + n0 + tx];
  }
  __syncthreads();
#pragma unroll
  for (int k = 0; k < 4; ++k) {
    int r = ty + k * 8;
    out[(size_t)(n0 + r) * 10240 + d0 + tx] = f2bf(tile[tx][r]);
  }
}

// ---------------------------------------------------------------------------
// Generic C(MxN) = A(MxD) * B(NxD)^T, bf16 MFMA 16x16x32, 128x128 tile, BK=32.
// AF32/BF32: operand is fp32 in global, converted to bf16 during LDS staging.
// grid (N/128, M/128, split); kChunk = D/split (mult of 32). useAtomic for split>1.
template <bool AF32, bool BF32>
__global__ __launch_bounds__(256) void gemm_bt(const void* __restrict__ Ap,
                                               const void* __restrict__ Bp,
                                               float* __restrict__ C,
                                               int Ddim, int Ncols, int kChunk, int useAtomic) {
  __shared__ unsigned short As[128 * 32];
  __shared__ unsigned short Bs[128 * 32];
  int tid = threadIdx.x;
  int lane = tid & 63, wave = tid >> 6;
  int wr = (wave >> 1) * 64, wc = (wave & 1) * 64;
  int m0 = blockIdx.y * 128, n0 = blockIdx.x * 128;
  int kBeg = blockIdx.z * kChunk, kEnd = kBeg + kChunk;
  int srow = tid >> 1, scol = (tid & 1) * 16;
  f32x4 zero = {0.f, 0.f, 0.f, 0.f};
  f32x4 acc[4][4];
#pragma unroll
  for (int i = 0; i < 4; ++i)
#pragma unroll
    for (int j = 0; j < 4; ++j) acc[i][j] = zero;

  int fr = lane & 15, fq = lane >> 4;

  for (int kk = kBeg; kk < kEnd; kk += 32) {
    // ---- stage A tile (rows m0.., cols kk..kk+31) ----
    if (AF32) {
      const float* A = (const float*)Ap;
      const float4* src = (const float4*)(A + (size_t)(m0 + srow) * Ddim + kk + scol);
      float4 v0 = src[0], v1 = src[1], v2 = src[2], v3 = src[3];
      float vals[16] = {v0.x, v0.y, v0.z, v0.w, v1.x, v1.y, v1.z, v1.w,
                        v2.x, v2.y, v2.z, v2.w, v3.x, v3.y, v3.z, v3.w};
      unsigned int pk[8];
#pragma unroll
      for (int e = 0; e < 8; ++e)
        pk[e] = (unsigned int)f2bf(vals[2 * e]) | ((unsigned int)f2bf(vals[2 * e + 1]) << 16);
      uint4* dst = (uint4*)&As[srow * 32 + scol];
      dst[0] = make_uint4(pk[0], pk[1], pk[2], pk[3]);
      dst[1] = make_uint4(pk[4], pk[5], pk[6], pk[7]);
    } else {
      const unsigned short* A = (const unsigned short*)Ap;
      const uint4* src = (const uint4*)(A + (size_t)(m0 + srow) * Ddim + kk + scol);
      uint4* dst = (uint4*)&As[srow * 32 + scol];
      dst[0] = src[0];
      dst[1] = src[1];
    }
    // ---- stage B tile (rows n0.., cols kk..kk+31) ----
    if (BF32) {
      const float* B = (const float*)Bp;
      const float4* src = (const float4*)(B + (size_t)(n0 + srow) * Ddim + kk + scol);
      float4 v0 = src[0], v1 = src[1], v2 = src[2], v3 = src[3];
      float vals[16] = {v0.x, v0.y, v0.z, v0.w, v1.x, v1.y, v1.z, v1.w,
                        v2.x, v2.y, v2.z, v2.w, v3.x, v3.y, v3.z, v3.w};
      unsigned int pk[8];
#pragma unroll
      for (int e = 0; e < 8; ++e)
        pk[e] = (unsigned int)f2bf(vals[2 * e]) | ((unsigned int)f2bf(vals[2 * e + 1]) << 16);
      uint4* dst = (uint4*)&Bs[srow * 32 + scol];
      dst[0] = make_uint4(pk[0], pk[1], pk[2], pk[3]);
      dst[1] = make_uint4(pk[4], pk[5], pk[6], pk[7]);
    } else {
      const unsigned short* B = (const unsigned short*)Bp;
      const uint4* src = (const uint4*)(B + (size_t)(n0 + srow) * Ddim + kk + scol);
      uint4* dst = (uint4*)&Bs[srow * 32 + scol];
      dst[0] = src[0];
      dst[1] = src[1];
    }
    __syncthreads();
    // ---- fragments + MFMA: A[m=lane&15][k=quad*8+j], C/D: col=lane&15, row=quad*4+reg ----
    short8 af[4], bf_[4];
#pragma unroll
    for (int i = 0; i < 4; ++i)
      af[i] = *(const short8*)&As[(wr + i * 16 + fr) * 32 + fq * 8];
#pragma unroll
    for (int j = 0; j < 4; ++j)
      bf_[j] = *(const short8*)&Bs[(wc + j * 16 + fr) * 32 + fq * 8];
#pragma unroll
    for (int i = 0; i < 4; ++i)
#pragma unroll
      for (int j = 0; j < 4; ++j)
        acc[i][j] = __builtin_amdgcn_mfma_f32_16x16x32_bf16(af[i], bf_[j], acc[i][j], 0, 0, 0);
    __syncthreads();
  }
  // ---- epilogue ----
#pragma unroll
  for (int i = 0; i < 4; ++i) {
#pragma unroll
    for (int j = 0; j < 4; ++j) {
      int mBase = m0 + wr + i * 16 + fq * 4;
      int nIdx = n0 + wc + j * 16 + fr;
#pragma unroll
      for (int r = 0; r < 4; ++r) {
        float v = acc[i][j][r];
        float* p = &C[(size_t)(mBase + r) * Ncols + nIdx];
        if (useAtomic) atomicAdd(p, v);
        else *p = v;
      }
    }
  }
}

// ---------------------------------------------------------------------------
// Sequential feedback loop in MC-dim:  u_t = p_t - y_t ; y_{t+1} = y_t + H_t u_t
// 256 persistent blocks, block b owns rows {2b, 2b+1}.
// NO flags, NO acquire/release in the loop: U is pre-filled with 0xFFFFFFFF
// (NaN sentinel); each u word is written exactly once with a RELAXED agent
// store, and consumers poll the exact words they need with RELAXED agent
// loads (coherence-point access, no cache invalidation).  Data == flag.
__global__ __launch_bounds__(256) void seq_kernel(const float* __restrict__ Cmat,
                                                  const float* __restrict__ upert,
                                                  const float* __restrict__ bias,
                                                  const float* __restrict__ phi_stu,
                                                  float* __restrict__ U) {
  __shared__ float plds[2][T_DIM];   // p_t for owned rows (4 KB)
  __shared__ float red[2][2][4];     // [t parity][row][wave]
  int tid = threadIdx.x;
  int b = blockIdx.x;
  int c0 = 2 * b, c1 = 2 * b + 1;
  int ca = tid, cb = tid + 256;
  int wv = tid >> 6, ln = tid & 63;

  // C slice -> registers: Creg[r][j][f] = Cmat[(c0+r)*10240 + f*512 + (j? cb : ca)]
  // 80 fp32 VGPRs/thread; loads are wave-coalesced per (r,f,j).
  float Creg[2][2][NF_DIM];
#pragma unroll
  for (int r = 0; r < 2; ++r)
#pragma unroll
    for (int f = 0; f < NF_DIM; ++f) {
      Creg[r][0][f] = Cmat[(size_t)(c0 + r) * 10240 + f * 512 + ca];
      Creg[r][1][f] = Cmat[(size_t)(c0 + r) * 10240 + f * 512 + cb];
    }
  for (int t = tid; t < T_DIM; t += 256) {
    plds[0][t] = upert[(size_t)t * MC_DIM + c0] + bias[c0];
    plds[1][t] = upert[(size_t)t * MC_DIM + c1] + bias[c1];
  }
  __syncthreads();

  float y0 = 0.f, y1 = 0.f;   // state lives in thread 0's registers

  for (int t = 0; t < T_DIM; ++t) {
    if (tid == 0) {
      float u0 = plds[0][t] - y0;
      float u1 = plds[1][t] - y1;
      __hip_atomic_store(&U[(size_t)t * MC_DIM + c0], u0, __ATOMIC_RELAXED, __HIP_MEMORY_SCOPE_AGENT);
      __hip_atomic_store(&U[(size_t)t * MC_DIM + c1], u1, __ATOMIC_RELAXED, __HIP_MEMORY_SCOPE_AGENT);
    }
    if (t == T_DIM - 1) break;

    // poll the two u_t words this thread needs (bit-pattern sentinel check)
    unsigned int va, vb;
    const unsigned int* pa = (const unsigned int*)&U[(size_t)t * MC_DIM + ca];
    const unsigned int* pb = (const unsigned int*)&U[(size_t)t * MC_DIM + cb];
    do { va = __hip_atomic_load(pa, __ATOMIC_RELAXED, __HIP_MEMORY_SCOPE_AGENT); } while (va == 0xFFFFFFFFu);
    do { vb = __hip_atomic_load(pb, __ATOMIC_RELAXED, __HIP_MEMORY_SCOPE_AGENT); } while (vb == 0xFFFFFFFFu);
    float ua = __uint_as_float(va);
    float ub = __uint_as_float(vb);

    // partial of H_t u_t for rows c0,c1 (phi_stu via scalar-cached uniform loads)
    float p0 = 0.f, p1 = 0.f;
#pragma unroll
    for (int f = 0; f < NF_DIM; ++f) {
      float wf = phi_stu[t * NF_DIM + f];
      p0 += wf * (Creg[0][0][f] * ua + Creg[0][1][f] * ub);
      p1 += wf * (Creg[1][0][f] * ua + Creg[1][1][f] * ub);
    }
#pragma unroll
    for (int off = 32; off > 0; off >>= 1) {
      p0 += __shfl_down(p0, off);
      p1 += __shfl_down(p1, off);
    }
    int par = t & 1;
    if (ln == 0) { red[par][0][wv] = p0; red[par][1][wv] = p1; }
    __syncthreads();
    if (tid == 0) {
      y0 += red[par][0][0] + red[par][0][1] + red[par][0][2] + red[par][0][3];
      y1 += red[par][1][0] + red[par][1][1] + red[par][1][2] + red[par][1][3];
    }
  }
}

// Rp[t][(f,c)] = phi_stu[t,f] * U[t,c]   (bf16)   grid (10240/256, T)
__global__ __launch_bounds__(256) void rp_kernel(const float* __restrict__ U,
                                                 const float* __restrict__ phi_stu,
                                                 unsigned short* __restrict__ Rp) {
  int t = blockIdx.y;
  int j = blockIdx.x * 256 + threadIdx.x;
  int f = j >> 9, c = j & 511;
  Rp[(size_t)t * 10240 + j] = f2bf(phi_stu[t * NF_DIM + f] * U[(size_t)t * MC_DIM + c]);
}

// ---- chunked exclusive prefix over t of G (T x N) -> X ----
__global__ __launch_bounds__(256) void scan1_kernel(const float* __restrict__ G, float* __restrict__ Psum) {
  int n = blockIdx.x * 256 + threadIdx.x;
  int c = blockIdx.y;
  float s = 0.f;
  for (int j = 0; j < 32; ++j) s += G[(size_t)(c * 32 + j) * N_DIM + n];
  Psum[c * N_DIM + n] = s;
}
__global__ __launch_bounds__(256) void scan2_kernel(float* __restrict__ Psum) {
  int n = blockIdx.x * 256 + threadIdx.x;
  float run = 0.f;
  for (int c = 0; c < 16; ++c) {
    float v = Psum[c * N_DIM + n];
    Psum[c * N_DIM + n] = run;
    run += v;
  }
}
__global__ __launch_bounds__(256) void scan3_kernel(const float* __restrict__ G, const float* __restrict__ Psum,
                                                    float* __restrict__ X) {
  int n = blockIdx.x * 256 + threadIdx.x;
  int c = blockIdx.y;
  float x = Psum[c * N_DIM + n];
  for (int j = 0; j < 32; ++j) {
    int t = c * 32 + j;
    X[(size_t)t * N_DIM + n] = x;
    x += G[(size_t)t * N_DIM + n];
  }
}

// losses[t] = dot(XQ[t], X[t]) + dot(UR[t], U[t])
__global__ __launch_bounds__(256) void loss_kernel(const float* __restrict__ XQ, const float* __restrict__ X,
                                                   const float* __restrict__ UR, const float* __restrict__ U,
                                                   float* __restrict__ out) {
  int t = blockIdx.x, tid = threadIdx.x;
  float s = 0.f;
  for (int j = tid; j < N_DIM; j += 256) s += XQ[(size_t)t * N_DIM + j] * X[(size_t)t * N_DIM + j];
  for (int c = tid; c < MC_DIM; c += 256) s += UR[(size_t)t * MC_DIM + c] * U[(size_t)t * MC_DIM + c];
#pragma unroll
  for (int off = 32; off > 0; off >>= 1) s += __shfl_down(s, off);
  __shared__ float red[4];
  if ((tid & 63) == 0) red[tid >> 6] = s;
  __syncthreads();
  if (tid == 0) out[t] = red[0] + red[1] + red[2] + red[3];
}

// ---------------------------------------------------------------------------
extern "C" void kernel_launch(void* const* d_in, const int* in_sizes, int n_in,
                              void* d_out, int out_size, void* d_ws, size_t ws_size,
                              hipStream_t stream) {
  const float* Q      = (const float*)d_in[0];
  const float* R      = (const float*)d_in[1];
  const float* Km     = (const float*)d_in[2];
  const float* E      = (const float*)d_in[3];
  const float* bias   = (const float*)d_in[4];
  const float* Estu   = (const float*)d_in[5];
  const float* phi    = (const float*)d_in[6];
  const float* sigma  = (const float*)d_in[7];
  const float* phistu = (const float*)d_in[8];
  const float* W      = (const float*)d_in[9];
  float* out = (float*)d_out;

  char* ws = (char*)d_ws;
  size_t off = 0;
  auto alloc = [&](size_t bytes) -> void* {
    void* p = ws + off;
    off += (bytes + 255) & ~(size_t)255;
    return p;
  };
  // split-K outputs (contiguous -> single memset)
  float* upert = (float*)alloc((size_t)512 * 512 * 4);    // 1 MB
  float* G     = (float*)alloc((size_t)512 * 1024 * 4);   // 2 MB
  float* XQ    = (float*)alloc((size_t)512 * 1024 * 4);   // 2 MB
  float* UR    = (float*)alloc((size_t)512 * 512 * 4);    // 1 MB
  float* Cmat  = (float*)alloc((size_t)512 * 10240 * 4);  // 20 MB
  float* U     = (float*)alloc((size_t)512 * 512 * 4);    // 1 MB
  float* X     = (float*)alloc((size_t)512 * 1024 * 4);   // 2 MB
  float* Psum  = (float*)alloc((size_t)16 * 1024 * 4);    // 64 KB
  unsigned short* WWb  = (unsigned short*)alloc((size_t)512 * 5120 * 2);   // 5 MB
  unsigned short* Escb = (unsigned short*)alloc((size_t)512 * 5120 * 2);   // 5 MB
  unsigned short* Et2  = (unsigned short*)alloc((size_t)1024 * 10240 * 2); // 20 MB
  unsigned short* Rp   = WWb;  // alias: WWb+Escb (10 MB) dead after GEMM1; Rp needs 10 MB

  hipMemsetAsync(upert, 0, (size_t)6291456, stream);      // upert,G,XQ,UR (split-K accum)
  hipMemsetAsync(U, 0xFF, (size_t)512 * 512 * 4, stream); // NaN sentinel for data-as-flag

  ww_kernel<<<dim3(4, 512), 256, 0, stream>>>(W, phi, WWb);
  esc_kernel<<<dim3(4, 512), 256, 0, stream>>>(E, sigma, Escb);
  transpose_conv_kernel<<<dim3(320, 32), 256, 0, stream>>>(Estu, Et2);

  // u_pert_raw(512x512) = WW(512x5120) * Esc(512x5120)^T   [split-K 8]
  gemm_bt<false, false><<<dim3(4, 4, 8), 256, 0, stream>>>(WWb, Escb, upert, 5120, 512, 640, 1);
  // Cmat(512x10240) = K(512x1024,f32) * Estu(10240x1024,f32)^T
  gemm_bt<true, true><<<dim3(80, 4, 1), 256, 0, stream>>>(Km, Estu, Cmat, 1024, 10240, 1024, 0);

  // sequential feedback loop -> U (512x512)
  seq_kernel<<<dim3(256), 256, 0, stream>>>(Cmat, upert, bias, phistu, U);

  // G(512x1024) = Rp(512x10240) * Et2(1024x10240)^T   [split-K 4]
  rp_kernel<<<dim3(40, 512), 256, 0, stream>>>(U, phistu, Rp);
  gemm_bt<false, false><<<dim3(8, 4, 4), 256, 0, stream>>>(Rp, Et2, G, 10240, 1024, 2560, 1);

  scan1_kernel<<<dim3(4, 16), 256, 0, stream>>>(G, Psum);
  scan2_kernel<<<dim3(4), 256, 0, stream>>>(Psum);
  scan3_kernel<<<dim3(4, 16), 256, 0, stream>>>(G, Psum, X);

  // XQ(512x1024) = X(512x1024,f32) * Q(1024x1024,f32)^T   [split-K 4]
  gemm_bt<true, true><<<dim3(8, 4, 4), 256, 0, stream>>>(X, Q, XQ, 1024, 1024, 256, 1);
  // UR(512x512)  = U(512x512,f32) * R(512x512,f32)^T      [split-K 8]
  gemm_bt<true, true><<<dim3(4, 4, 8), 256, 0, stream>>>(U, R, UR, 512, 512, 64, 1);

  loss_kernel<<<dim3(512), 256, 0, stream>>>(XQ, X, UR, U, out);
  (void)in_sizes; (void)n_in; (void)out_size; (void)ws_size;
}

// Round 3
// 1260.709 us; speedup vs baseline: 10.0828x; 1.6691x over previous
//
#include <hip/hip_runtime.h>

// Problem constants (from reference): T=512, N=1024, MC=512, H=5, M=20, NF=20
#define T_DIM 512
#define N_DIM 1024
#define MC_DIM 512
#define H_DIM 5
#define M_WIN 20
#define NF_DIM 20

typedef __attribute__((ext_vector_type(8))) short short8;
typedef __attribute__((ext_vector_type(4))) float f32x4;

__device__ __forceinline__ unsigned short f2bf(float f) {
  unsigned int u = __float_as_uint(f);
  u += 0x7fffu + ((u >> 16) & 1u);   // round-to-nearest-even
  return (unsigned short)(u >> 16);
}

// ---------------------------------------------------------------------------
// WW[t,i,n] = sum_k phi[k,i] * Wpad[t+k, n]  (bf16 out, layout [t][i][n])
// grid (N/256, T)
__global__ __launch_bounds__(256) void ww_kernel(const float* __restrict__ W,
                                                 const float* __restrict__ phi,
                                                 unsigned short* __restrict__ WWb) {
  __shared__ float phis[M_WIN * H_DIM];
  int tid = threadIdx.x;
  if (tid < M_WIN * H_DIM) phis[tid] = phi[tid];
  __syncthreads();
  int n = blockIdx.x * 256 + tid;
  int t = blockIdx.y;
  float acc[H_DIM] = {0.f, 0.f, 0.f, 0.f, 0.f};
  int k0 = 19 - t; if (k0 < 0) k0 = 0;
  for (int k = k0; k < M_WIN; ++k) {
    float wv = W[(t + k - 19) * N_DIM + n];
#pragma unroll
    for (int i = 0; i < H_DIM; ++i) acc[i] += phis[k * H_DIM + i] * wv;
  }
#pragma unroll
  for (int i = 0; i < H_DIM; ++i)
    WWb[(size_t)(t * H_DIM + i) * N_DIM + n] = f2bf(acc[i]);
}

// Esc[c,i,n] = sigma[i]^0.25 * E[c,n,i]   (bf16 out, layout [c][i][n])
// grid (N/256, MC)
__global__ __launch_bounds__(256) void esc_kernel(const float* __restrict__ E,
                                                  const float* __restrict__ sigma,
                                                  unsigned short* __restrict__ Escb) {
  int tid = threadIdx.x;
  int n = blockIdx.x * 256 + tid;
  int c = blockIdx.y;
#pragma unroll
  for (int i = 0; i < H_DIM; ++i) {
    float s4 = powf(sigma[i], 0.25f);
    float v = E[((size_t)c * N_DIM + n) * H_DIM + i] * s4;
    Escb[(size_t)(c * H_DIM + i) * N_DIM + n] = f2bf(v);
  }
}

// Et2[n][(f,c)] = E_stu[f,c,n]  fp32 (10240 x 1024) -> bf16 (1024 x 10240) transpose
// grid (10240/32, 1024/32), block 256 (32x8)
__global__ __launch_bounds__(256) void transpose_conv_kernel(const float* __restrict__ in,
                                                             unsigned short* __restrict__ out) {
  __shared__ float tile[32][33];
  int tx = threadIdx.x & 31, ty = threadIdx.x >> 5;
  int d0 = blockIdx.x * 32, n0 = blockIdx.y * 32;
#pragma unroll
  for (int k = 0; k < 4; ++k) {
    int r = ty + k * 8;
    tile[r][tx] = in[(size_t)(d0 + r) * N_DIM + n0 + tx];
  }
  __syncthreads();
#pragma unroll
  for (int k = 0; k < 4; ++k) {
    int r = ty + k * 8;
    out[(size_t)(n0 + r) * 10240 + d0 + tx] = f2bf(tile[tx][r]);
  }
}

// ---------------------------------------------------------------------------
// Generic C(MxN) = A(MxD) * B(NxD)^T, bf16 MFMA 16x16x32, 128x128 tile, BK=32.
// AF32/BF32: operand is fp32 in global, converted to bf16 during LDS staging.
// grid (N/128, M/128, split); kChunk = D/split (mult of 32). useAtomic for split>1.
template <bool AF32, bool BF32>
__global__ __launch_bounds__(256) void gemm_bt(const void* __restrict__ Ap,
                                               const void* __restrict__ Bp,
                                               float* __restrict__ C,
                                               int Ddim, int Ncols, int kChunk, int useAtomic) {
  __shared__ unsigned short As[128 * 32];
  __shared__ unsigned short Bs[128 * 32];
  int tid = threadIdx.x;
  int lane = tid & 63, wave = tid >> 6;
  int wr = (wave >> 1) * 64, wc = (wave & 1) * 64;
  int m0 = blockIdx.y * 128, n0 = blockIdx.x * 128;
  int kBeg = blockIdx.z * kChunk, kEnd = kBeg + kChunk;
  int srow = tid >> 1, scol = (tid & 1) * 16;
  f32x4 zero = {0.f, 0.f, 0.f, 0.f};
  f32x4 acc[4][4];
#pragma unroll
  for (int i = 0; i < 4; ++i)
#pragma unroll
    for (int j = 0; j < 4; ++j) acc[i][j] = zero;

  int fr = lane & 15, fq = lane >> 4;

  for (int kk = kBeg; kk < kEnd; kk += 32) {
    // ---- stage A tile (rows m0.., cols kk..kk+31) ----
    if (AF32) {
      const float* A = (const float*)Ap;
      const float4* src = (const float4*)(A + (size_t)(m0 + srow) * Ddim + kk + scol);
      float4 v0 = src[0], v1 = src[1], v2 = src[2], v3 = src[3];
      float vals[16] = {v0.x, v0.y, v0.z, v0.w, v1.x, v1.y, v1.z, v1.w,
                        v2.x, v2.y, v2.z, v2.w, v3.x, v3.y, v3.z, v3.w};
      unsigned int pk[8];
#pragma unroll
      for (int e = 0; e < 8; ++e)
        pk[e] = (unsigned int)f2bf(vals[2 * e]) | ((unsigned int)f2bf(vals[2 * e + 1]) << 16);
      uint4* dst = (uint4*)&As[srow * 32 + scol];
      dst[0] = make_uint4(pk[0], pk[1], pk[2], pk[3]);
      dst[1] = make_uint4(pk[4], pk[5], pk[6], pk[7]);
    } else {
      const unsigned short* A = (const unsigned short*)Ap;
      const uint4* src = (const uint4*)(A + (size_t)(m0 + srow) * Ddim + kk + scol);
      uint4* dst = (uint4*)&As[srow * 32 + scol];
      dst[0] = src[0];
      dst[1] = src[1];
    }
    // ---- stage B tile (rows n0.., cols kk..kk+31) ----
    if (BF32) {
      const float* B = (const float*)Bp;
      const float4* src = (const float4*)(B + (size_t)(n0 + srow) * Ddim + kk + scol);
      float4 v0 = src[0], v1 = src[1], v2 = src[2], v3 = src[3];
      float vals[16] = {v0.x, v0.y, v0.z, v0.w, v1.x, v1.y, v1.z, v1.w,
                        v2.x, v2.y, v2.z, v2.w, v3.x, v3.y, v3.z, v3.w};
      unsigned int pk[8];
#pragma unroll
      for (int e = 0; e < 8; ++e)
        pk[e] = (unsigned int)f2bf(vals[2 * e]) | ((unsigned int)f2bf(vals[2 * e + 1]) << 16);
      uint4* dst = (uint4*)&Bs[srow * 32 + scol];
      dst[0] = make_uint4(pk[0], pk[1], pk[2], pk[3]);
      dst[1] = make_uint4(pk[4], pk[5], pk[6], pk[7]);
    } else {
      const unsigned short* B = (const unsigned short*)Bp;
      const uint4* src = (const uint4*)(B + (size_t)(n0 + srow) * Ddim + kk + scol);
      uint4* dst = (uint4*)&Bs[srow * 32 + scol];
      dst[0] = src[0];
      dst[1] = src[1];
    }
    __syncthreads();
    // ---- fragments + MFMA: A[m=lane&15][k=quad*8+j], C/D: col=lane&15, row=quad*4+reg ----
    short8 af[4], bf_[4];
#pragma unroll
    for (int i = 0; i < 4; ++i)
      af[i] = *(const short8*)&As[(wr + i * 16 + fr) * 32 + fq * 8];
#pragma unroll
    for (int j = 0; j < 4; ++j)
      bf_[j] = *(const short8*)&Bs[(wc + j * 16 + fr) * 32 + fq * 8];
#pragma unroll
    for (int i = 0; i < 4; ++i)
#pragma unroll
      for (int j = 0; j < 4; ++j)
        acc[i][j] = __builtin_amdgcn_mfma_f32_16x16x32_bf16(af[i], bf_[j], acc[i][j], 0, 0, 0);
    __syncthreads();
  }
  // ---- epilogue ----
#pragma unroll
  for (int i = 0; i < 4; ++i) {
#pragma unroll
    for (int j = 0; j < 4; ++j) {
      int mBase = m0 + wr + i * 16 + fq * 4;
      int nIdx = n0 + wc + j * 16 + fr;
#pragma unroll
      for (int r = 0; r < 4; ++r) {
        float v = acc[i][j][r];
        float* p = &C[(size_t)(mBase + r) * Ncols + nIdx];
        if (useAtomic) atomicAdd(p, v);
        else *p = v;
      }
    }
  }
}

// ---------------------------------------------------------------------------
// Sequential feedback loop in MC-dim:  u_t = p_t - y_t ; y_{t+1} = y_t + H_t u_t
// 256 persistent blocks, block b owns u components {2b, 2b+1}.
// Data-as-flag with 8x REPLICATED publication: writer thread0 packs (u0,u1)
// into one 64-bit word and stores it to 8 replica buffers (relaxed agent,
// fire-and-forget, parallel at the coherence point). Block b polls replica
// (b&7) -> per-cacheline reader count drops 256 -> 32 (slice-queue relief).
// Single 64-bit atomic poll per thread per step (atomicity => both halves
// valid once != sentinel). C-slice in VGPRs (launch_bounds(256,2) so the 80
// floats don't spill); phi_stu staged to LDS.
__global__ __launch_bounds__(256, 2) void seq_kernel(const float* __restrict__ Cmat,
                                                     const float* __restrict__ upert,
                                                     const float* __restrict__ bias,
                                                     const float* __restrict__ phi_stu,
                                                     float* __restrict__ Urep) {
  __shared__ float phis[T_DIM * NF_DIM];  // 40 KB
  __shared__ float plds[2][T_DIM];        // 4 KB
  __shared__ float red[2][2][4];          // [t parity][row][wave]
  int tid = threadIdx.x;
  int b = blockIdx.x;
  int c0 = 2 * b, c1 = c0 + 1;
  int ja = 2 * tid;                       // columns {ja, ja+1} handled by this thread
  int wv = tid >> 6, ln = tid & 63;

  // C slice -> registers: Creg[r][j][f] = Cmat[(c0+r)*10240 + f*512 + ja+j]
  float Creg[2][2][NF_DIM];
#pragma unroll
  for (int r = 0; r < 2; ++r)
#pragma unroll
    for (int f = 0; f < NF_DIM; ++f) {
      const float2 cv = *(const float2*)&Cmat[(size_t)(c0 + r) * 10240 + f * 512 + ja];
      Creg[r][0][f] = cv.x;
      Creg[r][1][f] = cv.y;
    }
  for (int t = tid; t < T_DIM; t += 256) {
    plds[0][t] = upert[(size_t)t * MC_DIM + c0] + bias[c0];
    plds[1][t] = upert[(size_t)t * MC_DIM + c1] + bias[c1];
  }
  for (int i = tid; i < T_DIM * NF_DIM; i += 256) phis[i] = phi_stu[i];
  __syncthreads();

  unsigned long long* Uw = (unsigned long long*)Urep;
  const unsigned long long* Ur =
      (const unsigned long long*)(Urep + (size_t)(b & 7) * (T_DIM * MC_DIM));

  float y0 = 0.f, y1 = 0.f;   // state lives in thread 0's registers

  for (int t = 0; t < T_DIM; ++t) {
    if (tid == 0) {
      float u0 = plds[0][t] - y0;
      float u1 = plds[1][t] - y1;
      unsigned long long pk =
          ((unsigned long long)__float_as_uint(u1) << 32) | (unsigned long long)__float_as_uint(u0);
      size_t w0 = ((size_t)t * MC_DIM + c0) >> 1;
#pragma unroll
      for (int r = 0; r < 8; ++r)
        __hip_atomic_store(&Uw[(size_t)r * (T_DIM * MC_DIM / 2) + w0], pk,
                           __ATOMIC_RELAXED, __HIP_MEMORY_SCOPE_AGENT);
    }
    if (t == T_DIM - 1) break;

    // single packed poll of this thread's two u_t components
    unsigned long long v;
    const unsigned long long* pa = &Ur[((size_t)t * MC_DIM + ja) >> 1];
    do { v = __hip_atomic_load(pa, __ATOMIC_RELAXED, __HIP_MEMORY_SCOPE_AGENT); }
    while (v == 0xFFFFFFFFFFFFFFFFull);
    float ua = __uint_as_float((unsigned int)v);
    float ub = __uint_as_float((unsigned int)(v >> 32));

    // partial of H_t u_t for rows c0,c1
    float p0 = 0.f, p1 = 0.f;
    const float* w = &phis[t * NF_DIM];
#pragma unroll
    for (int f = 0; f < NF_DIM; ++f) {
      float wf = w[f];
      p0 += wf * (Creg[0][0][f] * ua + Creg[0][1][f] * ub);
      p1 += wf * (Creg[1][0][f] * ua + Creg[1][1][f] * ub);
    }
#pragma unroll
    for (int off = 32; off > 0; off >>= 1) {
      p0 += __shfl_down(p0, off);
      p1 += __shfl_down(p1, off);
    }
    int par = t & 1;
    if (ln == 0) { red[par][0][wv] = p0; red[par][1][wv] = p1; }
    __syncthreads();
    if (tid == 0) {
      y0 += red[par][0][0] + red[par][0][1] + red[par][0][2] + red[par][0][3];
      y1 += red[par][1][0] + red[par][1][1] + red[par][1][2] + red[par][1][3];
    }
  }
}

// Rp[t][(f,c)] = phi_stu[t,f] * U[t,c]   (bf16)   grid (10240/256, T)
__global__ __launch_bounds__(256) void rp_kernel(const float* __restrict__ U,
                                                 const float* __restrict__ phi_stu,
                                                 unsigned short* __restrict__ Rp) {
  int t = blockIdx.y;
  int j = blockIdx.x * 256 + threadIdx.x;
  int f = j >> 9, c = j & 511;
  Rp[(size_t)t * 10240 + j] = f2bf(phi_stu[t * NF_DIM + f] * U[(size_t)t * MC_DIM + c]);
}

// ---- chunked exclusive prefix over t of G (T x N) -> X ----
__global__ __launch_bounds__(256) void scan1_kernel(const float* __restrict__ G, float* __restrict__ Psum) {
  int n = blockIdx.x * 256 + threadIdx.x;
  int c = blockIdx.y;
  float s = 0.f;
  for (int j = 0; j < 32; ++j) s += G[(size_t)(c * 32 + j) * N_DIM + n];
  Psum[c * N_DIM + n] = s;
}
__global__ __launch_bounds__(256) void scan2_kernel(float* __restrict__ Psum) {
  int n = blockIdx.x * 256 + threadIdx.x;
  float run = 0.f;
  for (int c = 0; c < 16; ++c) {
    float v = Psum[c * N_DIM + n];
    Psum[c * N_DIM + n] = run;
    run += v;
  }
}
__global__ __launch_bounds__(256) void scan3_kernel(const float* __restrict__ G, const float* __restrict__ Psum,
                                                    float* __restrict__ X) {
  int n = blockIdx.x * 256 + threadIdx.x;
  int c = blockIdx.y;
  float x = Psum[c * N_DIM + n];
  for (int j = 0; j < 32; ++j) {
    int t = c * 32 + j;
    X[(size_t)t * N_DIM + n] = x;
    x += G[(size_t)t * N_DIM + n];
  }
}

// losses[t] = dot(XQ[t], X[t]) + dot(UR[t], U[t])
__global__ __launch_bounds__(256) void loss_kernel(const float* __restrict__ XQ, const float* __restrict__ X,
                                                   const float* __restrict__ UR, const float* __restrict__ U,
                                                   float* __restrict__ out) {
  int t = blockIdx.x, tid = threadIdx.x;
  float s = 0.f;
  for (int j = tid; j < N_DIM; j += 256) s += XQ[(size_t)t * N_DIM + j] * X[(size_t)t * N_DIM + j];
  for (int c = tid; c < MC_DIM; c += 256) s += UR[(size_t)t * MC_DIM + c] * U[(size_t)t * MC_DIM + c];
#pragma unroll
  for (int off = 32; off > 0; off >>= 1) s += __shfl_down(s, off);
  __shared__ float red[4];
  if ((tid & 63) == 0) red[tid >> 6] = s;
  __syncthreads();
  if (tid == 0) out[t] = red[0] + red[1] + red[2] + red[3];
}

// ---------------------------------------------------------------------------
extern "C" void kernel_launch(void* const* d_in, const int* in_sizes, int n_in,
                              void* d_out, int out_size, void* d_ws, size_t ws_size,
                              hipStream_t stream) {
  const float* Q      = (const float*)d_in[0];
  const float* R      = (const float*)d_in[1];
  const float* Km     = (const float*)d_in[2];
  const float* E      = (const float*)d_in[3];
  const float* bias   = (const float*)d_in[4];
  const float* Estu   = (const float*)d_in[5];
  const float* phi    = (const float*)d_in[6];
  const float* sigma  = (const float*)d_in[7];
  const float* phistu = (const float*)d_in[8];
  const float* W      = (const float*)d_in[9];
  float* out = (float*)d_out;

  char* ws = (char*)d_ws;
  size_t off = 0;
  auto alloc = [&](size_t bytes) -> void* {
    void* p = ws + off;
    off += (bytes + 255) & ~(size_t)255;
    return p;
  };
  // split-K outputs (contiguous -> single memset)
  float* upert = (float*)alloc((size_t)512 * 512 * 4);    // 1 MB
  float* G     = (float*)alloc((size_t)512 * 1024 * 4);   // 2 MB
  float* XQ    = (float*)alloc((size_t)512 * 1024 * 4);   // 2 MB
  float* UR    = (float*)alloc((size_t)512 * 512 * 4);    // 1 MB
  float* Cmat  = (float*)alloc((size_t)512 * 10240 * 4);  // 20 MB
  float* Urep  = (float*)alloc((size_t)8 * 512 * 512 * 4); // 8 MB (8 replicas)
  float* X     = (float*)alloc((size_t)512 * 1024 * 4);   // 2 MB
  float* Psum  = (float*)alloc((size_t)16 * 1024 * 4);    // 64 KB
  unsigned short* WWb  = (unsigned short*)alloc((size_t)512 * 5120 * 2);   // 5 MB
  unsigned short* Escb = (unsigned short*)alloc((size_t)512 * 5120 * 2);   // 5 MB
  unsigned short* Et2  = (unsigned short*)alloc((size_t)1024 * 10240 * 2); // 20 MB
  unsigned short* Rp   = WWb;  // alias: WWb+Escb (10 MB) dead after GEMM1; Rp needs 10 MB
  float* U = Urep;             // replica 0 serves downstream consumers

  hipMemsetAsync(upert, 0, (size_t)6291456, stream);          // upert,G,XQ,UR (split-K accum)
  hipMemsetAsync(Urep, 0xFF, (size_t)8 * 512 * 512 * 4, stream); // sentinel for data-as-flag

  ww_kernel<<<dim3(4, 512), 256, 0, stream>>>(W, phi, WWb);
  esc_kernel<<<dim3(4, 512), 256, 0, stream>>>(E, sigma, Escb);
  transpose_conv_kernel<<<dim3(320, 32), 256, 0, stream>>>(Estu, Et2);

  // u_pert_raw(512x512) = WW(512x5120) * Esc(512x5120)^T   [split-K 8]
  gemm_bt<false, false><<<dim3(4, 4, 8), 256, 0, stream>>>(WWb, Escb, upert, 5120, 512, 640, 1);
  // Cmat(512x10240) = K(512x1024,f32) * Estu(10240x1024,f32)^T
  gemm_bt<true, true><<<dim3(80, 4, 1), 256, 0, stream>>>(Km, Estu, Cmat, 1024, 10240, 1024, 0);

  // sequential feedback loop -> Urep (8 replicas of U 512x512)
  seq_kernel<<<dim3(256), 256, 0, stream>>>(Cmat, upert, bias, phistu, Urep);

  // G(512x1024) = Rp(512x10240) * Et2(1024x10240)^T   [split-K 4]
  rp_kernel<<<dim3(40, 512), 256, 0, stream>>>(U, phistu, Rp);
  gemm_bt<false, false><<<dim3(8, 4, 4), 256, 0, stream>>>(Rp, Et2, G, 10240, 1024, 2560, 1);

  scan1_kernel<<<dim3(4, 16), 256, 0, stream>>>(G, Psum);
  scan2_kernel<<<dim3(4), 256, 0, stream>>>(Psum);
  scan3_kernel<<<dim3(4, 16), 256, 0, stream>>>(G, Psum, X);

  // XQ(512x1024) = X(512x1024,f32) * Q(1024x1024,f32)^T   [split-K 4]
  gemm_bt<true, true><<<dim3(8, 4, 4), 256, 0, stream>>>(X, Q, XQ, 1024, 1024, 256, 1);
  // UR(512x512)  = U(512x512,f32) * R(512x512,f32)^T      [split-K 8]
  gemm_bt<true, true><<<dim3(4, 4, 8), 256, 0, stream>>>(U, R, UR, 512, 512, 64, 1);

  loss_kernel<<<dim3(512), 256, 0, stream>>>(XQ, X, UR, U, out);
  (void)in_sizes; (void)n_in; (void)out_size; (void)ws_size;
}